// Round 4
// baseline (329.609 us; speedup 1.0000x reference)
//
#include <hip/hip_runtime.h>

#define FFT_N   4096
#define THREADS 256

__device__ __forceinline__ float2 cmul(float2 w, float2 v) {
    return make_float2(fmaf(w.x, v.x, -w.y * v.y), fmaf(w.x, v.y, w.y * v.x));
}
__device__ __forceinline__ float2 cmni(float2 v) { return make_float2(v.y, -v.x); }
__device__ __forceinline__ void bfly(float2& a, float2& b, float2 w) {
    float2 t = cmul(w, b);
    b = make_float2(a.x - t.x, a.y - t.y);
    a = make_float2(a.x + t.x, a.y + t.y);
}
// Pair-slot swizzle: fold bits 3..10 into the low-3 (bank-quad) bits.
// Verified even residue spread for all 7 access patterns below; bijective.
__device__ __forceinline__ int sslot(int p) {
    return p ^ ((p >> 3) & 7) ^ ((p >> 6) & 7) ^ ((p >> 9) & 7);
}
// lgkmcnt-only barrier: prefetched global loads stay in flight (no vmcnt drain).
__device__ __forceinline__ void bar() {
    asm volatile("s_waitcnt lgkmcnt(0)" ::: "memory");
    __builtin_amdgcn_s_barrier();
}
// radix-8 = 3 radix-2 stages on u[j] = element (base + j*s).
__device__ __forceinline__ void radix8(float2 u[8], float2 A, float2 B, float2 C, float2 D) {
    bfly(u[0], u[1], A); bfly(u[2], u[3], A); bfly(u[4], u[5], A); bfly(u[6], u[7], A);
    float2 Bn = cmni(B);
    bfly(u[0], u[2], B); bfly(u[1], u[3], Bn); bfly(u[4], u[6], B); bfly(u[5], u[7], Bn);
    float2 Cn = cmni(C), Dn = cmni(D);
    bfly(u[0], u[4], C); bfly(u[1], u[5], D); bfly(u[2], u[6], Cn); bfly(u[3], u[7], Dn);
}

__device__ __forceinline__ void nt_store_f2(float* p, float2 v) {
    union { float2 f; unsigned long long u; } cv; cv.f = v;
    __builtin_nontemporal_store(cv.u, (unsigned long long*)p);
}

struct RowBuf { float2 re[8]; float2 im[8]; };

// Coalesced float2 loads: lanes read elements (2t, 2t+1) + 512*rev3(j).
__device__ __forceinline__ void load_row(RowBuf& rb, const float* __restrict__ xr,
                                         const float* __restrict__ xi, int t2) {
    const int off[8] = {0, 2048, 1024, 3072, 512, 2560, 1536, 3584};
#pragma unroll
    for (int j = 0; j < 8; ++j) {
        rb.re[j] = *(const float2*)(xr + t2 + off[j]);
        rb.im[j] = *(const float2*)(xi + t2 + off[j]);
    }
}

// LDS invariant: float4 slot p holds complex (y[p], y[p+2048]).
__device__ __forceinline__ void process_row(const RowBuf& rb, float4* lds, int t,
        float2 C1, float2 C2, float2 C3u, float2 C3v,
        float* __restrict__ yr, float* __restrict__ yi)
{
    const float2 one  = make_float2(1.f, 0.f);
    const float2 w512 = make_float2(0.70710678118654752f, -0.70710678118654752f);
    float2 u[8], v[8];

    // ---- pass 0: groups rev8(t) (lo) and rev8(t)+256 (hi); twiddles 1,1,1,W512.
#pragma unroll
    for (int j = 0; j < 8; ++j) {
        u[j] = make_float2(rb.re[j].x, rb.im[j].x);
        v[j] = make_float2(rb.re[j].y, rb.im[j].y);
    }
    radix8(u, one, one, one, w512);
    radix8(v, one, one, one, w512);
    const int g = (int)(__brev((unsigned)t) >> 24);   // rev8(t)
#pragma unroll
    for (int j = 0; j < 8; ++j)
        lds[sslot(8 * g + j)] = make_float4(u[j].x, u[j].y, v[j].x, v[j].y);
    bar();

    // ---- pass 1: groups a1, a1+2048 (shared twiddles, r1 = t&7).
    const int a1 = (t & 7) | ((t >> 3) << 6);
#pragma unroll
    for (int j = 0; j < 8; ++j) {
        float4 f = lds[sslot(a1 + 8 * j)];
        u[j] = make_float2(f.x, f.y); v[j] = make_float2(f.z, f.w);
    }
    { float2 B = cmul(C1, C1), A = cmul(B, B), D = cmul(C1, w512);
      radix8(u, A, B, C1, D); radix8(v, A, B, C1, D); }
#pragma unroll
    for (int j = 0; j < 8; ++j)
        lds[sslot(a1 + 8 * j)] = make_float4(u[j].x, u[j].y, v[j].x, v[j].y);
    bar();

    // ---- pass 2: groups a2, a2+2048 (shared twiddles, r2 = t&63).
    const int a2 = (t & 63) | ((t >> 6) << 9);
#pragma unroll
    for (int j = 0; j < 8; ++j) {
        float4 f = lds[sslot(a2 + 64 * j)];
        u[j] = make_float2(f.x, f.y); v[j] = make_float2(f.z, f.w);
    }
    { float2 B = cmul(C2, C2), A = cmul(B, B), D = cmul(C2, w512);
      radix8(u, A, B, C2, D); radix8(v, A, B, C2, D); }
#pragma unroll
    for (int j = 0; j < 8; ++j)
        lds[sslot(a2 + 64 * j)] = make_float4(u[j].x, u[j].y, v[j].x, v[j].y);
    bar();

    // ---- pass 3: groups c=2t (u) and c+1 (v); slot c+512j holds (u[j], u[j+4]).
    const int c = 2 * t;
#pragma unroll
    for (int j = 0; j < 4; ++j) {
        float4 f0 = lds[sslot(c + 512 * j)];
        float4 f1 = lds[sslot(c + 1 + 512 * j)];
        u[j] = make_float2(f0.x, f0.y); u[j + 4] = make_float2(f0.z, f0.w);
        v[j] = make_float2(f1.x, f1.y); v[j + 4] = make_float2(f1.z, f1.w);
    }
    { float2 B = cmul(C3u, C3u), A = cmul(B, B), D = cmul(C3u, w512);
      radix8(u, A, B, C3u, D); }
    { float2 B = cmul(C3v, C3v), A = cmul(B, B), D = cmul(C3v, w512);
      radix8(v, A, B, C3v, D); }
    // thread holds y[2t+512j] (u) and y[2t+1+512j] (v) -> coalesced NT float2 stores.
#pragma unroll
    for (int j = 0; j < 8; ++j) {
        nt_store_f2(yr + c + 512 * j, make_float2(u[j].x, v[j].x));
        nt_store_f2(yi + c + 512 * j, make_float2(u[j].y, v[j].y));
    }
    bar();   // pass-3 reads done before next row's pass-0 scatter reuses LDS
}

__global__ __launch_bounds__(THREADS, 4) void fft4096_p2_kernel(
    const float* __restrict__ x_re, const float* __restrict__ x_im,
    const float* __restrict__ W_re, const float* __restrict__ W_im,
    float* __restrict__ out, int batch, int rows_per)
{
    __shared__ float4 lds[FFT_N / 2];   // 32 KB, pair-interleaved
    const int t = threadIdx.x;

    // Row-invariant twiddle bases (B=C^2, A=B^2, D=C*W512 derived per pass).
    const float2 C1 = make_float2(W_re[(t & 7) << 6],  W_im[(t & 7) << 6]);
    const float2 C2 = make_float2(W_re[(t & 63) << 3], W_im[(t & 63) << 3]);
    const float2 wr2 = ((const float2*)W_re)[t];   // (W[2t], W[2t+1]) re
    const float2 wi2 = ((const float2*)W_im)[t];
    const float2 C3u = make_float2(wr2.x, wi2.x);
    const float2 C3v = make_float2(wr2.y, wi2.y);

    const int t2 = 2 * t;
    const int row0 = blockIdx.x * rows_per;
    RowBuf ra, rb;

    if (rows_per & 1) {   // generic fallback (not hit for batch=8192)
        for (int i = 0; i < rows_per; ++i) {
            const int r = row0 + i;
            load_row(ra, x_re + (size_t)r * FFT_N, x_im + (size_t)r * FFT_N, t2);
            process_row(ra, lds, t, C1, C2, C3u, C3v,
                        out + (size_t)r * FFT_N, out + ((size_t)batch + r) * FFT_N);
        }
        return;
    }

    // 2-deep row pipeline: next row's 16 float2 loads issue before current compute.
    load_row(ra, x_re + (size_t)row0 * FFT_N, x_im + (size_t)row0 * FFT_N, t2);
    for (int i = 0; i < rows_per; i += 2) {
        const int r0 = row0 + i, r1 = r0 + 1;
        load_row(rb, x_re + (size_t)r1 * FFT_N, x_im + (size_t)r1 * FFT_N, t2);
        process_row(ra, lds, t, C1, C2, C3u, C3v,
                    out + (size_t)r0 * FFT_N, out + ((size_t)batch + r0) * FFT_N);
        if (i + 2 < rows_per) {
            const int r2 = r0 + 2;
            load_row(ra, x_re + (size_t)r2 * FFT_N, x_im + (size_t)r2 * FFT_N, t2);
        }
        process_row(rb, lds, t, C1, C2, C3u, C3v,
                    out + (size_t)r1 * FFT_N, out + ((size_t)batch + r1) * FFT_N);
    }
}

extern "C" void kernel_launch(void* const* d_in, const int* in_sizes, int n_in,
                              void* d_out, int out_size, void* d_ws, size_t ws_size,
                              hipStream_t stream) {
    const float* x_re = (const float*)d_in[0];
    const float* x_im = (const float*)d_in[1];
    const float* W_re = (const float*)d_in[2];
    const float* W_im = (const float*)d_in[3];
    // d_in[4] = bitrev (unused: bit-reversal folded into the pass-0 load pattern)
    const int batch = in_sizes[0] / FFT_N;
    float* out = (float*)d_out;

    int rows_per = 8;
    while (rows_per > 1 && (batch % rows_per)) rows_per >>= 1;
    const int grid = batch / rows_per;
    fft4096_p2_kernel<<<grid, THREADS, 0, stream>>>(x_re, x_im, W_re, W_im, out, batch, rows_per);
}

// Round 5
// 115.040 us; speedup vs baseline: 2.8652x; 2.8652x over previous
//
#include <hip/hip_runtime.h>

#define FFT_N   4096
#define THREADS 256

__device__ __forceinline__ float2 cmul(float2 w, float2 v) {
    return make_float2(fmaf(w.x, v.x, -w.y * v.y), fmaf(w.x, v.y, w.y * v.x));
}
__device__ __forceinline__ float2 cmni(float2 v) { return make_float2(v.y, -v.x); }
__device__ __forceinline__ void bfly(float2& a, float2& b, float2 w) {
    float2 t = cmul(w, b);
    b = make_float2(a.x - t.x, a.y - t.y);
    a = make_float2(a.x + t.x, a.y + t.y);
}
// Pair-slot swizzle: fold bits 3..10 into the low-3 (bank-quad) bits.
__device__ __forceinline__ int sslot(int p) {
    return p ^ ((p >> 3) & 7) ^ ((p >> 6) & 7) ^ ((p >> 9) & 7);
}
// lgkmcnt-only barrier: prefetched global loads stay in flight (no vmcnt drain).
__device__ __forceinline__ void bar() {
    asm volatile("s_waitcnt lgkmcnt(0)" ::: "memory");
    __builtin_amdgcn_s_barrier();
}
// radix-8 = 3 radix-2 stages on u[j] = element (base + j*s).
__device__ __forceinline__ void radix8(float2 u[8], float2 A, float2 B, float2 C, float2 D) {
    bfly(u[0], u[1], A); bfly(u[2], u[3], A); bfly(u[4], u[5], A); bfly(u[6], u[7], A);
    float2 Bn = cmni(B);
    bfly(u[0], u[2], B); bfly(u[1], u[3], Bn); bfly(u[4], u[6], B); bfly(u[5], u[7], Bn);
    float2 Cn = cmni(C), Dn = cmni(D);
    bfly(u[0], u[4], C); bfly(u[1], u[5], D); bfly(u[2], u[6], Cn); bfly(u[3], u[7], Dn);
}

struct RowBuf { float2 re[8]; float2 im[8]; };

// Coalesced float2 loads: lanes read elements (2t, 2t+1) + 512*rev3(j) -> 512B/wave-instr.
__device__ __forceinline__ void load_row(RowBuf& rb, const float* __restrict__ xr,
                                         const float* __restrict__ xi, int t2) {
    const int off[8] = {0, 2048, 1024, 3072, 512, 2560, 1536, 3584};
#pragma unroll
    for (int j = 0; j < 8; ++j) {
        rb.re[j] = *(const float2*)(xr + t2 + off[j]);
        rb.im[j] = *(const float2*)(xi + t2 + off[j]);
    }
}

// LDS invariant: float4 slot p holds complex (y[p], y[p+2048]).
__device__ __forceinline__ void process_row(const RowBuf& rb, float4* lds, int t,
        float2 C1, float2 C2, float2 C3u, float2 C3v,
        float* __restrict__ yr, float* __restrict__ yi)
{
    const float2 one  = make_float2(1.f, 0.f);
    const float2 w512 = make_float2(0.70710678118654752f, -0.70710678118654752f);
    float2 u[8], v[8];

    // ---- pass 0: groups rev8(t) (lo) and rev8(t)+256 (hi); twiddles 1,1,1,W512.
#pragma unroll
    for (int j = 0; j < 8; ++j) {
        u[j] = make_float2(rb.re[j].x, rb.im[j].x);
        v[j] = make_float2(rb.re[j].y, rb.im[j].y);
    }
    radix8(u, one, one, one, w512);
    radix8(v, one, one, one, w512);
    const int g = (int)(__brev((unsigned)t) >> 24);   // rev8(t)
#pragma unroll
    for (int j = 0; j < 8; ++j)
        lds[sslot(8 * g + j)] = make_float4(u[j].x, u[j].y, v[j].x, v[j].y);
    bar();

    // ---- pass 1: groups a1, a1+2048 (shared twiddles, r1 = t&7).
    const int a1 = (t & 7) | ((t >> 3) << 6);
#pragma unroll
    for (int j = 0; j < 8; ++j) {
        float4 f = lds[sslot(a1 + 8 * j)];
        u[j] = make_float2(f.x, f.y); v[j] = make_float2(f.z, f.w);
    }
    { float2 B = cmul(C1, C1), A = cmul(B, B), D = cmul(C1, w512);
      radix8(u, A, B, C1, D); radix8(v, A, B, C1, D); }
#pragma unroll
    for (int j = 0; j < 8; ++j)
        lds[sslot(a1 + 8 * j)] = make_float4(u[j].x, u[j].y, v[j].x, v[j].y);
    bar();

    // ---- pass 2: groups a2, a2+2048 (shared twiddles, r2 = t&63).
    const int a2 = (t & 63) | ((t >> 6) << 9);
#pragma unroll
    for (int j = 0; j < 8; ++j) {
        float4 f = lds[sslot(a2 + 64 * j)];
        u[j] = make_float2(f.x, f.y); v[j] = make_float2(f.z, f.w);
    }
    { float2 B = cmul(C2, C2), A = cmul(B, B), D = cmul(C2, w512);
      radix8(u, A, B, C2, D); radix8(v, A, B, C2, D); }
#pragma unroll
    for (int j = 0; j < 8; ++j)
        lds[sslot(a2 + 64 * j)] = make_float4(u[j].x, u[j].y, v[j].x, v[j].y);
    bar();

    // ---- pass 3: groups c=2t (u) and c+1 (v); slot c+512j holds (u[j], u[j+4]).
    const int c = 2 * t;
#pragma unroll
    for (int j = 0; j < 4; ++j) {
        float4 f0 = lds[sslot(c + 512 * j)];
        float4 f1 = lds[sslot(c + 1 + 512 * j)];
        u[j] = make_float2(f0.x, f0.y); u[j + 4] = make_float2(f0.z, f0.w);
        v[j] = make_float2(f1.x, f1.y); v[j + 4] = make_float2(f1.z, f1.w);
    }
    { float2 B = cmul(C3u, C3u), A = cmul(B, B), D = cmul(C3u, w512);
      radix8(u, A, B, C3u, D); }
    { float2 B = cmul(C3v, C3v), A = cmul(B, B), D = cmul(C3v, w512);
      radix8(v, A, B, C3v, D); }
    // thread holds y[2t+512j] (u) and y[2t+1+512j] (v) -> coalesced float2 stores (512B/wave).
#pragma unroll
    for (int j = 0; j < 8; ++j) {
        *(float2*)(yr + c + 512 * j) = make_float2(u[j].x, v[j].x);
        *(float2*)(yi + c + 512 * j) = make_float2(u[j].y, v[j].y);
    }
    bar();   // pass-3 reads done before next row's pass-0 scatter reuses LDS
}

__global__ __launch_bounds__(THREADS) void fft4096_p2_kernel(
    const float* __restrict__ x_re, const float* __restrict__ x_im,
    const float* __restrict__ W_re, const float* __restrict__ W_im,
    float* __restrict__ out, int batch, int rows_per)
{
    __shared__ float4 lds[FFT_N / 2];   // 32 KB, pair-interleaved
    const int t = threadIdx.x;

    // Row-invariant twiddle bases (B=C^2, A=B^2, D=C*W512 derived per pass).
    const float2 C1 = make_float2(W_re[(t & 7) << 6],  W_im[(t & 7) << 6]);
    const float2 C2 = make_float2(W_re[(t & 63) << 3], W_im[(t & 63) << 3]);
    const float2 wr2 = ((const float2*)W_re)[t];   // (W[2t], W[2t+1]) re
    const float2 wi2 = ((const float2*)W_im)[t];
    const float2 C3u = make_float2(wr2.x, wi2.x);
    const float2 C3v = make_float2(wr2.y, wi2.y);

    const int t2 = 2 * t;
    const int row0 = blockIdx.x * rows_per;
    RowBuf ra, rb;

    if (rows_per & 1) {   // generic fallback (not hit for batch=8192)
        for (int i = 0; i < rows_per; ++i) {
            const int r = row0 + i;
            load_row(ra, x_re + (size_t)r * FFT_N, x_im + (size_t)r * FFT_N, t2);
            process_row(ra, lds, t, C1, C2, C3u, C3v,
                        out + (size_t)r * FFT_N, out + ((size_t)batch + r) * FFT_N);
        }
        return;
    }

    // 2-deep row pipeline: next row's 16 float2 loads issue before current compute.
    load_row(ra, x_re + (size_t)row0 * FFT_N, x_im + (size_t)row0 * FFT_N, t2);
    for (int i = 0; i < rows_per; i += 2) {
        const int r0 = row0 + i, r1 = r0 + 1;
        load_row(rb, x_re + (size_t)r1 * FFT_N, x_im + (size_t)r1 * FFT_N, t2);
        process_row(ra, lds, t, C1, C2, C3u, C3v,
                    out + (size_t)r0 * FFT_N, out + ((size_t)batch + r0) * FFT_N);
        if (i + 2 < rows_per) {
            const int r2 = r0 + 2;
            load_row(ra, x_re + (size_t)r2 * FFT_N, x_im + (size_t)r2 * FFT_N, t2);
        }
        process_row(rb, lds, t, C1, C2, C3u, C3v,
                    out + (size_t)r1 * FFT_N, out + ((size_t)batch + r1) * FFT_N);
    }
}

extern "C" void kernel_launch(void* const* d_in, const int* in_sizes, int n_in,
                              void* d_out, int out_size, void* d_ws, size_t ws_size,
                              hipStream_t stream) {
    const float* x_re = (const float*)d_in[0];
    const float* x_im = (const float*)d_in[1];
    const float* W_re = (const float*)d_in[2];
    const float* W_im = (const float*)d_in[3];
    // d_in[4] = bitrev (unused: bit-reversal folded into the pass-0 load pattern)
    const int batch = in_sizes[0] / FFT_N;
    float* out = (float*)d_out;

    int rows_per = 8;
    while (rows_per > 1 && (batch % rows_per)) rows_per >>= 1;
    const int grid = batch / rows_per;
    fft4096_p2_kernel<<<grid, THREADS, 0, stream>>>(x_re, x_im, W_re, W_im, out, batch, rows_per);
}

// Round 6
// 109.132 us; speedup vs baseline: 3.0203x; 1.0541x over previous
//
#include <hip/hip_runtime.h>

#define FFT_N   4096
#define THREADS 512

__device__ __forceinline__ float2 cmul(float2 w, float2 v) {
    return make_float2(fmaf(w.x, v.x, -w.y * v.y), fmaf(w.x, v.y, w.y * v.x));
}
__device__ __forceinline__ float2 cmni(float2 v) { return make_float2(v.y, -v.x); }
__device__ __forceinline__ void bfly(float2& a, float2& b, float2 w) {
    float2 t = cmul(w, b);
    b = make_float2(a.x - t.x, a.y - t.y);
    a = make_float2(a.x + t.x, a.y + t.y);
}
// XOR-fold swizzle (verified round 2: conflicts 1.7e7 -> ~1e6).
__device__ __forceinline__ int swz(int i) { return i ^ ((i >> 4) & 15) ^ ((i >> 8) & 15); }

// lgkmcnt-only barrier: prefetched global loads stay in flight (no vmcnt drain).
__device__ __forceinline__ void bar() {
    asm volatile("s_waitcnt lgkmcnt(0)" ::: "memory");
    __builtin_amdgcn_s_barrier();
}
// radix-8 = 3 radix-2 stages on u[j] = element (base + j*s).
__device__ __forceinline__ void radix8(float2 u[8], float2 A, float2 B, float2 C, float2 D) {
    bfly(u[0], u[1], A); bfly(u[2], u[3], A); bfly(u[4], u[5], A); bfly(u[6], u[7], A);
    float2 Bn = cmni(B);
    bfly(u[0], u[2], B); bfly(u[1], u[3], Bn); bfly(u[4], u[6], B); bfly(u[5], u[7], Bn);
    float2 Cn = cmni(C), Dn = cmni(D);
    bfly(u[0], u[4], C); bfly(u[1], u[5], D); bfly(u[2], u[6], Cn); bfly(u[3], u[7], Dn);
}

struct Row { float2 u[8]; };

// Bit-reversed coalesced pattern: u[j] = x[t + 512*rev3(j)].
__device__ __forceinline__ void load_row(Row& r, const float* __restrict__ xr,
                                         const float* __restrict__ xi, int t) {
    const int off[8] = {0, 2048, 1024, 3072, 512, 2560, 1536, 3584};
#pragma unroll
    for (int j = 0; j < 8; ++j) r.u[j] = make_float2(xr[t + off[j]], xi[t + off[j]]);
}

// Issue 2 complex prefetch loads (4 dwords), then PIN them with a memory
// clobber so the compiler cannot sink them to the use site (round-5 lesson:
// VGPR==data-size proves the prefetch was being sunk).
__device__ __forceinline__ void issue2(Row& n, int a, int b, int offa, int offb,
                                       const float* __restrict__ xr,
                                       const float* __restrict__ xi, int t, bool en) {
    if (en) {
        n.u[a] = make_float2(xr[t + offa], xi[t + offa]);
        n.u[b] = make_float2(xr[t + offb], xi[t + offb]);
    }
    asm volatile("" ::: "memory");
}

// 4 radix-8 passes; next row's 16 loads issued 4-per-phase (right after each
// barrier) so HBM request arrival is smooth and each chunk has >=1 phase of
// latency cover before consumption.
__device__ __forceinline__ void process_row(Row& r, float2* lds, int t,
        float2 C1, float2 C2, float2 C3, float2 w512,
        float* __restrict__ yr, float* __restrict__ yi,
        Row& nxt, const float* __restrict__ nxr, const float* __restrict__ nxi, bool en)
{
    const float2 one = make_float2(1.f, 0.f);

    // ---- pass 0 (stages 0..2): twiddles 1,1,1,W512.
    issue2(nxt, 0, 1, 0, 2048, nxr, nxi, t, en);
    radix8(r.u, one, one, one, w512);
    const int g0 = (int)(__brev((unsigned)t) >> 23);   // rev9(t)
#pragma unroll
    for (int j = 0; j < 8; ++j) lds[swz(8 * g0 + j)] = r.u[j];
    bar();

    // ---- pass 1 (stages 3..5)
    issue2(nxt, 2, 3, 1024, 3072, nxr, nxi, t, en);
    const int b1 = (t & 7) | (((t >> 4) & 1) << 6) | (((t >> 3) & 1) << 7) | ((t >> 5) << 8);
#pragma unroll
    for (int j = 0; j < 8; ++j) r.u[j] = lds[swz(b1 + 8 * j)];
    { float2 B = cmul(C1, C1), A = cmul(B, B), D = cmul(C1, w512);
      radix8(r.u, A, B, C1, D); }
#pragma unroll
    for (int j = 0; j < 8; ++j) lds[swz(b1 + 8 * j)] = r.u[j];   // same slots: no pre-barrier
    bar();

    // ---- pass 2 (stages 6..8)
    issue2(nxt, 4, 5, 512, 2560, nxr, nxi, t, en);
    const int b2 = (t & 63) | ((t >> 6) << 9);
#pragma unroll
    for (int j = 0; j < 8; ++j) r.u[j] = lds[swz(b2 + 64 * j)];
    { float2 B = cmul(C2, C2), A = cmul(B, B), D = cmul(C2, w512);
      radix8(r.u, A, B, C2, D); }
#pragma unroll
    for (int j = 0; j < 8; ++j) lds[swz(b2 + 64 * j)] = r.u[j];
    bar();

    // ---- pass 3 (stages 9..11): thread t ends holding y[t + 512j].
    issue2(nxt, 6, 7, 1536, 3584, nxr, nxi, t, en);
#pragma unroll
    for (int j = 0; j < 8; ++j) r.u[j] = lds[swz(t + 512 * j)];
    { float2 B = cmul(C3, C3), A = cmul(B, B), D = cmul(C3, w512);
      radix8(r.u, A, B, C3, D); }
#pragma unroll
    for (int j = 0; j < 8; ++j) { yr[t + 512 * j] = r.u[j].x; yi[t + 512 * j] = r.u[j].y; }
    bar();   // pass-3 reads done before next row's pass-0 scatter reuses LDS
}

__global__ __launch_bounds__(THREADS) void fft4096_pin_kernel(
    const float* __restrict__ x_re, const float* __restrict__ x_im,
    const float* __restrict__ W_re, const float* __restrict__ W_im,
    float* __restrict__ out, int batch, int rows_per)
{
    __shared__ float2 lds[FFT_N];
    const int t = threadIdx.x;

    // Row-invariant twiddle bases (B=C^2, A=B^2, D=C*W512 derived per pass).
    const float2 C1 = make_float2(W_re[(t & 7) << 6],  W_im[(t & 7) << 6]);
    const float2 C2 = make_float2(W_re[(t & 63) << 3], W_im[(t & 63) << 3]);
    const float2 C3 = make_float2(W_re[t],             W_im[t]);
    const float2 w512 = make_float2(0.70710678118654752f, -0.70710678118654752f);

    const int row0 = blockIdx.x * rows_per;
    Row A, B;

    if (rows_per & 1) {   // generic fallback (not hit for batch=8192)
        for (int i = 0; i < rows_per; ++i) {
            const int r = row0 + i;
            load_row(A, x_re + (size_t)r * FFT_N, x_im + (size_t)r * FFT_N, t);
            asm volatile("" ::: "memory");
            process_row(A, lds, t, C1, C2, C3, w512,
                        out + (size_t)r * FFT_N, out + ((size_t)batch + r) * FFT_N,
                        B, x_re, x_im, false);
        }
        return;
    }

    load_row(A, x_re + (size_t)row0 * FFT_N, x_im + (size_t)row0 * FFT_N, t);
    asm volatile("" ::: "memory");
    for (int i = 0; i < rows_per; i += 2) {
        const int r0 = row0 + i, r1 = r0 + 1;
        const bool en2 = (i + 2) < rows_per;
        const int r2 = en2 ? (r0 + 2) : row0;   // clamped ptr; loads gated by en2
        process_row(A, lds, t, C1, C2, C3, w512,
                    out + (size_t)r0 * FFT_N, out + ((size_t)batch + r0) * FFT_N,
                    B, x_re + (size_t)r1 * FFT_N, x_im + (size_t)r1 * FFT_N, true);
        process_row(B, lds, t, C1, C2, C3, w512,
                    out + (size_t)r1 * FFT_N, out + ((size_t)batch + r1) * FFT_N,
                    A, x_re + (size_t)r2 * FFT_N, x_im + (size_t)r2 * FFT_N, en2);
    }
}

extern "C" void kernel_launch(void* const* d_in, const int* in_sizes, int n_in,
                              void* d_out, int out_size, void* d_ws, size_t ws_size,
                              hipStream_t stream) {
    const float* x_re = (const float*)d_in[0];
    const float* x_im = (const float*)d_in[1];
    const float* W_re = (const float*)d_in[2];
    const float* W_im = (const float*)d_in[3];
    // d_in[4] = bitrev (unused: bit-reversal folded into the pass-0 load pattern)
    const int batch = in_sizes[0] / FFT_N;
    float* out = (float*)d_out;

    int rows_per = 8;
    while (rows_per > 1 && (batch % rows_per)) rows_per >>= 1;
    const int grid = batch / rows_per;
    fft4096_pin_kernel<<<grid, THREADS, 0, stream>>>(x_re, x_im, W_re, W_im, out, batch, rows_per);
}